// Round 6
// baseline (688.138 us; speedup 1.0000x reference)
//
#include <hip/hip_runtime.h>
#include <hip/hip_bf16.h>

typedef __bf16 bf16x8 __attribute__((ext_vector_type(8)));
typedef float f32x4 __attribute__((ext_vector_type(4)));
typedef unsigned short u16;

// ---------- helpers ----------
__device__ __forceinline__ float b2f(u16 u) {
  union { unsigned int i; float f; } v; v.i = ((unsigned int)u) << 16; return v.f;
}
__device__ __forceinline__ u16 f2b(float f) {  // RNE
  union { float f; unsigned int i; } v; v.f = f;
  unsigned int r = v.i + 0x7fffu + ((v.i >> 16) & 1u);
  return (u16)(r >> 16);
}
__device__ __forceinline__ void gld_lds16(const u16* g, u16* l) {
  __builtin_amdgcn_global_load_lds(
      (const __attribute__((address_space(1))) unsigned int*)g,
      (__attribute__((address_space(3))) unsigned int*)l, 16, 0, 0);
}

// ---------- constants ----------
// D=2048 H=16 KV=4 HD=128 L=128 B=2 S=2048
// proj columns: [0,2048)=Q(16 heads), [2048,2560)=K(4 kv), [2560,3072)=V(4 kv),
//               [3072,3200)=q_latent, [3200,3328)=kv_latent
#define NPROJ 3328

// ---------- convert x (f32) -> xb (bf16) ----------
__global__ __launch_bounds__(256) void cvt_x(const float* __restrict__ x, u16* __restrict__ xb) {
  int i = (blockIdx.x * 256 + threadIdx.x) * 4;   // grid covers 8,388,608 elems
  float4 v = *(const float4*)(x + i);
  u16 o[4] = { f2b(v.x), f2b(v.y), f2b(v.z), f2b(v.w) };
  *(uint2*)(xb + i) = *(uint2*)o;
}

// ---------- prep: Wt1 = [wq|wk|wv|wql|wkl]^T  (3328 x 2048), f32 -> bf16 ----------
__global__ __launch_bounds__(256) void prep_wt1(
    const float* __restrict__ wq, const float* __restrict__ wk, const float* __restrict__ wv,
    const float* __restrict__ wql, const float* __restrict__ wkl, u16* __restrict__ wt1) {
  __shared__ u16 lds[64][80];
  int bn = blockIdx.x % 52, bk = blockIdx.x / 52;
  int n0 = bn * 64, k0 = bk * 64;
  const float* src; int srcN, c0;
  if (n0 < 2048)      { src = wq;  srcN = 2048; c0 = n0; }
  else if (n0 < 2560) { src = wk;  srcN = 512;  c0 = n0 - 2048; }
  else if (n0 < 3072) { src = wv;  srcN = 512;  c0 = n0 - 2560; }
  else if (n0 < 3200) { src = wql; srcN = 128;  c0 = n0 - 3072; }
  else                { src = wkl; srcN = 128;  c0 = n0 - 3200; }
  int t = threadIdx.x;
  int row = t >> 2, cg = (t & 3) * 16;
  const float* p = src + (size_t)(k0 + row) * srcN + c0 + cg;
  u16 tmp[16];
#pragma unroll
  for (int g = 0; g < 4; ++g) {
    float4 v = *(const float4*)(p + g * 4);
    tmp[g*4+0] = f2b(v.x); tmp[g*4+1] = f2b(v.y);
    tmp[g*4+2] = f2b(v.z); tmp[g*4+3] = f2b(v.w);
  }
  *(uint4*)&lds[row][cg]     = *(uint4*)&tmp[0];
  *(uint4*)&lds[row][cg + 8] = *(uint4*)&tmp[8];
  __syncthreads();
  int n = t >> 2, kg = (t & 3) * 16;
  u16 ov[16];
#pragma unroll
  for (int i = 0; i < 16; ++i) ov[i] = lds[kg + i][n];
  u16* dst = wt1 + (size_t)(n0 + n) * 2048 + k0 + kg;
  *(uint4*)&dst[0] = *(uint4*)&ov[0];
  *(uint4*)&dst[8] = *(uint4*)&ov[8];
}

// ---------- prep: Wt2 = wo^T (2048 x 2048), f32 -> bf16 ----------
__global__ __launch_bounds__(256) void prep_wt2(const float* __restrict__ wo, u16* __restrict__ wt2) {
  __shared__ u16 lds[64][80];
  int bn = blockIdx.x & 31, bk = blockIdx.x >> 5;
  int n0 = bn * 64, k0 = bk * 64;
  int t = threadIdx.x;
  int row = t >> 2, cg = (t & 3) * 16;
  const float* p = wo + (size_t)(k0 + row) * 2048 + n0 + cg;
  u16 tmp[16];
#pragma unroll
  for (int g = 0; g < 4; ++g) {
    float4 v = *(const float4*)(p + g * 4);
    tmp[g*4+0] = f2b(v.x); tmp[g*4+1] = f2b(v.y);
    tmp[g*4+2] = f2b(v.z); tmp[g*4+3] = f2b(v.w);
  }
  *(uint4*)&lds[row][cg]     = *(uint4*)&tmp[0];
  *(uint4*)&lds[row][cg + 8] = *(uint4*)&tmp[8];
  __syncthreads();
  int n = t >> 2, kg = (t & 3) * 16;
  u16 ov[16];
#pragma unroll
  for (int i = 0; i < 16; ++i) ov[i] = lds[kg + i][n];
  u16* dst = wt2 + (size_t)(n0 + n) * 2048 + k0 + kg;
  *(uint4*)&dst[0] = *(uint4*)&ov[0];
  *(uint4*)&dst[8] = *(uint4*)&ov[8];
}

// ---------- rope cos/sin table: [2048][64] float2 ----------
__global__ __launch_bounds__(256) void rope_table(float2* __restrict__ cs) {
  int idx = blockIdx.x * 256 + threadIdx.x;  // 2048*64
  int p = idx >> 6, i = idx & 63;
  float invf = exp2f(-(float)i * 0.20762050593046938f);  // 10000^(-i/64)
  float a = (float)p * invf;
  cs[idx] = make_float2(cosf(a), sinf(a));
}

// ---------- GEMM: C(MxN) = A(MxK) @ Bt(NxK)^T, bf16 in, fp32 acc ----------
// 128x128 tile, BK=64, 4 waves (2x2 of 64x64), m97 structure.
// Output: f32 to Cf if Cf!=nullptr, else bf16 to C.
// If lat != nullptr: += lat[(b*128 + (s&127))*2048 + n]  (latent scramble add)
__global__ __launch_bounds__(256) void gemm_bf16(
    const u16* __restrict__ A, const u16* __restrict__ Bt, u16* __restrict__ C,
    float* __restrict__ Cf,
    int K, int lda, int ldb, int ldc, int nbn, const u16* __restrict__ lat) {
  __shared__ u16 As[128 * 64];
  __shared__ u16 Bs[128 * 64];
  int bm = blockIdx.x / nbn, bn = blockIdx.x % nbn;
  int m0 = bm * 128, n0 = bn * 128;
  int t = threadIdx.x;
  int lane = t & 63, wave = t >> 6;
  int wm = (wave >> 1) * 64, wn = (wave & 1) * 64;
  int lr = lane & 15, lg = lane >> 4;
  f32x4 acc[4][4] = {};
  for (int kt = 0; kt < K; kt += 64) {
    __syncthreads();
#pragma unroll
    for (int p = 0; p < 4; ++p) {
      int c = (p * 4 + wave) * 64 + lane;  // 0..1023 chunks of 16B
      int row = c >> 3, col = (c & 7) * 8;
      gld_lds16(A + (size_t)(m0 + row) * lda + kt + col, As + c * 8);
      gld_lds16(Bt + (size_t)(n0 + row) * ldb + kt + col, Bs + c * 8);
    }
    __syncthreads();
#pragma unroll
    for (int ks = 0; ks < 2; ++ks) {
      bf16x8 af[4], bj[4];
#pragma unroll
      for (int i = 0; i < 4; ++i)
        af[i] = *(const bf16x8*)(As + (wm + i * 16 + lr) * 64 + ks * 32 + lg * 8);
#pragma unroll
      for (int j = 0; j < 4; ++j)
        bj[j] = *(const bf16x8*)(Bs + (wn + j * 16 + lr) * 64 + ks * 32 + lg * 8);
#pragma unroll
      for (int i = 0; i < 4; ++i)
#pragma unroll
        for (int j = 0; j < 4; ++j)
          acc[i][j] = __builtin_amdgcn_mfma_f32_16x16x32_bf16(af[i], bj[j], acc[i][j], 0, 0, 0);
    }
  }
#pragma unroll
  for (int i = 0; i < 4; ++i)
#pragma unroll
    for (int j = 0; j < 4; ++j)
#pragma unroll
      for (int r = 0; r < 4; ++r) {
        int mm = m0 + wm + i * 16 + lg * 4 + r;
        int nn = n0 + wn + j * 16 + lr;
        float v = acc[i][j][r];
        if (lat) {
          int b = mm >> 11, s2 = mm & 2047;
          v += b2f(lat[(size_t)(b * 128 + (s2 & 127)) * 2048 + nn]);
        }
        if (Cf) Cf[(size_t)mm * ldc + nn] = v;
        else    C [(size_t)mm * ldc + nn] = f2b(v);
      }
}

// ---------- in-place RoPE on proj cols [0,2560) (20 heads x 128) ----------
__global__ __launch_bounds__(256) void rope_kernel(u16* __restrict__ proj, const float2* __restrict__ cs) {
  int row = blockIdx.x;        // 0..4095 (b*2048+s)
  int s = row & 2047;
  const float2* csrow = cs + (size_t)s * 64;
  u16* prow = proj + (size_t)row * NPROJ;
  for (int u = threadIdx.x; u < 1280; u += 256) {
    int h = u >> 6, i = u & 63;
    int base = h * 128 + i;    // Q heads 0..15 and K heads 16..19
    float2 c = csrow[i];
    float a = b2f(prow[base]), b = b2f(prow[base + 64]);
    prow[base]      = f2b(a * c.x - b * c.y);
    prow[base + 64] = f2b(b * c.x + a * c.y);
  }
}

// ---------- transpose V -> vt(b,kv,d,s) and kv_latent -> klt(b,l,s) ----------
__global__ __launch_bounds__(256) void transpose_v(const u16* __restrict__ proj,
                                                   u16* __restrict__ vt, u16* __restrict__ klt) {
  __shared__ u16 lds[64][80];
  int bid = blockIdx.x;
  int b = bid / 320, r = bid % 320;
  int ct = r / 32, st = r % 32;
  int c0 = ct < 8 ? 2560 + ct * 64 : 3200 + (ct - 8) * 64;
  int s0 = st * 64;
  int t = threadIdx.x;
  int srow = t >> 2, cg = (t & 3) * 16;
  const u16* p = proj + (size_t)(b * 2048 + s0 + srow) * NPROJ + c0 + cg;
  *(uint4*)&lds[srow][cg]     = *(const uint4*)p;
  *(uint4*)&lds[srow][cg + 8] = *(const uint4*)(p + 8);
  __syncthreads();
  int c = c0 + (t >> 2);
  int sg = (t & 3) * 16;
  u16 ov[16];
#pragma unroll
  for (int i = 0; i < 16; ++i) ov[i] = lds[sg + i][t >> 2];
  u16* dst;
  if (c < 3072) { int kv = (c - 2560) >> 7, d = (c - 2560) & 127;
                  dst = vt + ((size_t)(b * 4 + kv) * 128 + d) * 2048 + s0 + sg; }
  else          { int l = c - 3200;
                  dst = klt + (size_t)(b * 128 + l) * 2048 + s0 + sg; }
  *(uint4*)&dst[0] = *(uint4*)&ov[0];
  *(uint4*)&dst[8] = *(uint4*)&ov[8];
}

// ---------- flash attention (17 "heads": 16 GQA + 1 latent) ----------
// Barrier-free: K/V read directly from L2 (per-(b,hh) KV = 1MB, cache-resident;
// XCD-pinned via bid%8==g%8). P via per-wave LDS scratch only.
__global__ __launch_bounds__(256) void flash_attn(const u16* __restrict__ proj,
                                                  const u16* __restrict__ vt,
                                                  const u16* __restrict__ klt,
                                                  u16* __restrict__ acomb,
                                                  u16* __restrict__ latent) {
  __shared__ u16 Ps[4][16 * 72];  // per-wave [q][key], stride 72
  int bid = blockIdx.x;           // grid 40*32: bid = (31-qt)*40 + g, g<34 real
  int g = bid % 40;
  if (g >= 34) return;
  int qt = 31 - bid / 40;         // long blocks launch first
  int hh = g % 17;
  int b  = g / 17;
  int lane = threadIdx.x & 63, wave = threadIdx.x >> 6;
  int lr = lane & 15, lg = lane >> 4;

  int qcol = hh < 16 ? hh * 128 : 3072;
  int kcol = hh < 16 ? 2048 + (hh >> 2) * 128 : 3200;
  const u16* vsrc = hh < 16 ? vt + (size_t)(b * 4 + (hh >> 2)) * 128 * 2048
                            : klt + (size_t)b * 128 * 2048;

  int qbase = qt * 64 + wave * 16;
  const u16* qp = proj + (size_t)(b * 2048 + qbase) * NPROJ + qcol;
  bf16x8 aq[4];
#pragma unroll
  for (int ks = 0; ks < 4; ++ks)
    aq[ks] = *(const bf16x8*)(qp + (size_t)lr * NPROJ + ks * 32 + lg * 8);

  const u16* kbase = proj + (size_t)(b * 2048) * NPROJ + kcol;

  f32x4 o[8] = {};
  float m2[4]   = {-1e30f, -1e30f, -1e30f, -1e30f};
  float lsum[4] = {0.f, 0.f, 0.f, 0.f};
  const float scl = 0.08838834764831845f * 1.4426950408889634f;  // 128^-0.5 * log2e

  for (int kt = 0; kt <= qt; ++kt) {
    // scores: S = Q @ K^T  (16q x 64key), K fragments straight from L2
    const u16* kg = kbase + (size_t)(kt * 64) * NPROJ;
    f32x4 sv[4];
#pragma unroll
    for (int fr = 0; fr < 4; ++fr) {
      f32x4 a = {};
      const u16* krow = kg + (size_t)(fr * 16 + lr) * NPROJ + lg * 8;
#pragma unroll
      for (int ks = 0; ks < 4; ++ks) {
        bf16x8 bk = *(const bf16x8*)(krow + ks * 32);
        a = __builtin_amdgcn_mfma_f32_16x16x32_bf16(aq[ks], bk, a, 0, 0, 0);
      }
      sv[fr] = a;
    }
    // mask + scale (exp2 domain)
#pragma unroll
    for (int fr = 0; fr < 4; ++fr) {
      int key = kt * 64 + fr * 16 + lr;
#pragma unroll
      for (int r = 0; r < 4; ++r) {
        int q = qbase + lg * 4 + r;
        sv[fr][r] = (key <= q) ? sv[fr][r] * scl : -1e30f;
      }
    }
    // online softmax per row group
#pragma unroll
    for (int r = 0; r < 4; ++r) {
      float mx = fmaxf(fmaxf(sv[0][r], sv[1][r]), fmaxf(sv[2][r], sv[3][r]));
      mx = fmaxf(mx, __shfl_xor(mx, 1));
      mx = fmaxf(mx, __shfl_xor(mx, 2));
      mx = fmaxf(mx, __shfl_xor(mx, 4));
      mx = fmaxf(mx, __shfl_xor(mx, 8));
      float mn = fmaxf(m2[r], mx);
      float corr = exp2f(m2[r] - mn);
      m2[r] = mn;
      float rs = 0.f;
#pragma unroll
      for (int fr = 0; fr < 4; ++fr) {
        float pp = exp2f(sv[fr][r] - mn);
        sv[fr][r] = pp;
        rs += pp;
      }
      rs += __shfl_xor(rs, 1); rs += __shfl_xor(rs, 2);
      rs += __shfl_xor(rs, 4); rs += __shfl_xor(rs, 8);
      lsum[r] = lsum[r] * corr + rs;
#pragma unroll
      for (int cf = 0; cf < 8; ++cf) o[cf][r] *= corr;
    }
    // P -> per-wave LDS scratch (wave-private: no barrier needed)
    u16* ps = &Ps[wave][0];
#pragma unroll
    for (int fr = 0; fr < 4; ++fr)
#pragma unroll
      for (int r = 0; r < 4; ++r) {
        int q = lg * 4 + r;
        int key = fr * 16 + lr;
        ps[q * 72 + key] = f2b(sv[fr][r]);
      }
    // PV: O += P @ V   (A = P[16q x 64k], B = V^T[d][k] straight from L2)
    const u16* vg = vsrc + kt * 64 + lg * 8;
#pragma unroll
    for (int ks = 0; ks < 2; ++ks) {
      bf16x8 ap = *(const bf16x8*)(ps + lr * 72 + ks * 32 + lg * 8);
#pragma unroll
      for (int cf = 0; cf < 8; ++cf) {
        bf16x8 bv = *(const bf16x8*)(vg + (size_t)(cf * 16 + lr) * 2048 + ks * 32);
        o[cf] = __builtin_amdgcn_mfma_f32_16x16x32_bf16(ap, bv, o[cf], 0, 0, 0);
      }
    }
  }
  // epilogue
  u16* obase; size_t ostride;
  if (hh < 16) { obase = acomb + hh * 128; ostride = 2048; }
  else         { obase = latent;           ostride = 128; }
#pragma unroll
  for (int r = 0; r < 4; ++r) {
    float inv = 1.0f / lsum[r];
    int q = qbase + lg * 4 + r;
    u16* orow = obase + (size_t)(b * 2048 + q) * ostride;
#pragma unroll
    for (int cf = 0; cf < 8; ++cf)
      orow[cf * 16 + lr] = f2b(o[cf][r] * inv);
  }
}

// ---------- launch ----------
extern "C" void kernel_launch(void* const* d_in, const int* in_sizes, int n_in,
                              void* d_out, int out_size, void* d_ws, size_t ws_size,
                              hipStream_t stream) {
  const float* x   = (const float*)d_in[0];
  // d_in[1] mask (tril int32, start_pos=0) — causality hardcoded
  const float* wq  = (const float*)d_in[2];
  const float* wk  = (const float*)d_in[3];
  const float* wv  = (const float*)d_in[4];
  const float* wql = (const float*)d_in[5];
  const float* wkl = (const float*)d_in[6];
  const float* wo  = (const float*)d_in[7];
  // d_in[8] start_pos == 0

  // Workspace layout (55 MiB peak), lifetimes carefully aliased:
  //   proj   @        0 : 27,262,976  (GEMM1 -> flash);  wt2 (8.4MB) aliases @0 after flash
  //   wt1    @ 27262976 : 13,631,488  (GEMM1 only); afterwards this region holds:
  //       cs     @ 27262976 : 1,048,576
  //       vt     @ 28311552 : 4,194,304
  //       klt    @ 32505856 : 1,048,576
  //       latent @ 33554432 : 1,048,576
  //       lout   @ 34603008 : 1,048,576   (ends 35,651,584 < 40,894,464)
  //   xb     @ 40894464 : 16,777,216  (cvt_x -> GEMM1); acomb aliases after GEMM1
  //   total 57,671,680 bytes
  char* ws = (char*)d_ws;
  u16*    proj  = (u16*)(ws + 0);
  u16*    wt2   = (u16*)(ws + 0);
  u16*    wt1   = (u16*)(ws + 27262976);
  float2* cs    = (float2*)(ws + 27262976);
  u16*    vt    = (u16*)(ws + 28311552);
  u16*    klt   = (u16*)(ws + 32505856);
  u16*    latent= (u16*)(ws + 33554432);
  u16*    lout  = (u16*)(ws + 34603008);
  u16*    xb    = (u16*)(ws + 40894464);
  u16*    acomb = (u16*)(ws + 40894464);
  float*  out   = (float*)d_out;

  prep_wt1<<<52 * 32, 256, 0, stream>>>(wq, wk, wv, wql, wkl, wt1);
  cvt_x<<<8192, 256, 0, stream>>>(x, xb);
  // proj = x @ [wq|wk|wv|wql|wkl]
  gemm_bf16<<<32 * 26, 256, 0, stream>>>(xb, wt1, proj, nullptr, 2048, 2048, 2048, NPROJ, 26, nullptr);
  rope_table<<<512, 256, 0, stream>>>(cs);          // wt1 dead from here
  rope_kernel<<<4096, 256, 0, stream>>>(proj, cs);
  transpose_v<<<640, 256, 0, stream>>>(proj, vt, klt);
  flash_attn<<<40 * 32, 256, 0, stream>>>(proj, vt, klt, acomb, latent);  // xb dead
  // wt2 = wo^T (into dead proj space)
  prep_wt2<<<32 * 32, 256, 0, stream>>>(wo, wt2);
  // lout = view(latent,(2x128,2048)) @ wo   (bf16 out)
  gemm_bf16<<<2 * 16, 256, 0, stream>>>(latent, wt2, lout, nullptr, 2048, 2048, 2048, 2048, 16, nullptr);
  // out(f32) = acomb @ wo + lout[b, s&127]  (latent reshape-scramble fused)
  gemm_bf16<<<32 * 16, 256, 0, stream>>>(acomb, wt2, nullptr, out, 2048, 2048, 2048, 2048, 16, lout);
}

// Round 7
// 670.254 us; speedup vs baseline: 1.0267x; 1.0267x over previous
//
#include <hip/hip_runtime.h>
#include <hip/hip_bf16.h>

typedef __bf16 bf16x8 __attribute__((ext_vector_type(8)));
typedef float f32x4 __attribute__((ext_vector_type(4)));
typedef unsigned short u16;

// ---------- helpers ----------
__device__ __forceinline__ float b2f(u16 u) {
  union { unsigned int i; float f; } v; v.i = ((unsigned int)u) << 16; return v.f;
}
__device__ __forceinline__ u16 f2b(float f) {  // RNE
  union { float f; unsigned int i; } v; v.f = f;
  unsigned int r = v.i + 0x7fffu + ((v.i >> 16) & 1u);
  return (u16)(r >> 16);
}
__device__ __forceinline__ void gld_lds16(const u16* g, u16* l) {
  __builtin_amdgcn_global_load_lds(
      (const __attribute__((address_space(1))) unsigned int*)g,
      (__attribute__((address_space(3))) unsigned int*)l, 16, 0, 0);
}

// ---------- constants ----------
// D=2048 H=16 KV=4 HD=128 L=128 B=2 S=2048
// proj columns: [0,2048)=Q(16 heads), [2048,2560)=K(4 kv), [2560,3072)=V(4 kv),
//               [3072,3200)=q_latent, [3200,3328)=kv_latent
#define NPROJ 3328

// ---------- convert x (f32) -> xb (bf16) ----------
__global__ __launch_bounds__(256) void cvt_x(const float* __restrict__ x, u16* __restrict__ xb) {
  int i = (blockIdx.x * 256 + threadIdx.x) * 4;   // grid covers 8,388,608 elems
  float4 v = *(const float4*)(x + i);
  u16 o[4] = { f2b(v.x), f2b(v.y), f2b(v.z), f2b(v.w) };
  *(uint2*)(xb + i) = *(uint2*)o;
}

// ---------- prep: Wt1 = [wq|wk|wv|wql|wkl]^T  (3328 x 2048), f32 -> bf16 ----------
__global__ __launch_bounds__(256) void prep_wt1(
    const float* __restrict__ wq, const float* __restrict__ wk, const float* __restrict__ wv,
    const float* __restrict__ wql, const float* __restrict__ wkl, u16* __restrict__ wt1) {
  __shared__ u16 lds[64][80];
  int bn = blockIdx.x % 52, bk = blockIdx.x / 52;
  int n0 = bn * 64, k0 = bk * 64;
  const float* src; int srcN, c0;
  if (n0 < 2048)      { src = wq;  srcN = 2048; c0 = n0; }
  else if (n0 < 2560) { src = wk;  srcN = 512;  c0 = n0 - 2048; }
  else if (n0 < 3072) { src = wv;  srcN = 512;  c0 = n0 - 2560; }
  else if (n0 < 3200) { src = wql; srcN = 128;  c0 = n0 - 3072; }
  else                { src = wkl; srcN = 128;  c0 = n0 - 3200; }
  int t = threadIdx.x;
  int row = t >> 2, cg = (t & 3) * 16;
  const float* p = src + (size_t)(k0 + row) * srcN + c0 + cg;
  u16 tmp[16];
#pragma unroll
  for (int g = 0; g < 4; ++g) {
    float4 v = *(const float4*)(p + g * 4);
    tmp[g*4+0] = f2b(v.x); tmp[g*4+1] = f2b(v.y);
    tmp[g*4+2] = f2b(v.z); tmp[g*4+3] = f2b(v.w);
  }
  *(uint4*)&lds[row][cg]     = *(uint4*)&tmp[0];
  *(uint4*)&lds[row][cg + 8] = *(uint4*)&tmp[8];
  __syncthreads();
  int n = t >> 2, kg = (t & 3) * 16;
  u16 ov[16];
#pragma unroll
  for (int i = 0; i < 16; ++i) ov[i] = lds[kg + i][n];
  u16* dst = wt1 + (size_t)(n0 + n) * 2048 + k0 + kg;
  *(uint4*)&dst[0] = *(uint4*)&ov[0];
  *(uint4*)&dst[8] = *(uint4*)&ov[8];
}

// ---------- prep: Wt2 = wo^T (2048 x 2048), f32 -> bf16 ----------
__global__ __launch_bounds__(256) void prep_wt2(const float* __restrict__ wo, u16* __restrict__ wt2) {
  __shared__ u16 lds[64][80];
  int bn = blockIdx.x & 31, bk = blockIdx.x >> 5;
  int n0 = bn * 64, k0 = bk * 64;
  int t = threadIdx.x;
  int row = t >> 2, cg = (t & 3) * 16;
  const float* p = wo + (size_t)(k0 + row) * 2048 + n0 + cg;
  u16 tmp[16];
#pragma unroll
  for (int g = 0; g < 4; ++g) {
    float4 v = *(const float4*)(p + g * 4);
    tmp[g*4+0] = f2b(v.x); tmp[g*4+1] = f2b(v.y);
    tmp[g*4+2] = f2b(v.z); tmp[g*4+3] = f2b(v.w);
  }
  *(uint4*)&lds[row][cg]     = *(uint4*)&tmp[0];
  *(uint4*)&lds[row][cg + 8] = *(uint4*)&tmp[8];
  __syncthreads();
  int n = t >> 2, kg = (t & 3) * 16;
  u16 ov[16];
#pragma unroll
  for (int i = 0; i < 16; ++i) ov[i] = lds[kg + i][n];
  u16* dst = wt2 + (size_t)(n0 + n) * 2048 + k0 + kg;
  *(uint4*)&dst[0] = *(uint4*)&ov[0];
  *(uint4*)&dst[8] = *(uint4*)&ov[8];
}

// ---------- rope cos/sin table: [2048][64] float2 ----------
__global__ __launch_bounds__(256) void rope_table(float2* __restrict__ cs) {
  int idx = blockIdx.x * 256 + threadIdx.x;  // 2048*64
  int p = idx >> 6, i = idx & 63;
  float invf = exp2f(-(float)i * 0.20762050593046938f);  // 10000^(-i/64)
  float a = (float)p * invf;
  cs[idx] = make_float2(cosf(a), sinf(a));
}

// ---------- GEMM: C(MxN) = A(MxK) @ Bt(NxK)^T, bf16 in, fp32 acc ----------
// 128x128 tile, BK=64, 4 waves (2x2 of 64x64), m97 structure.
// Output: f32 to Cf if Cf!=nullptr, else bf16 to C.
// If lat != nullptr: += lat[(b*128 + (s&127))*2048 + n]  (latent scramble add)
__global__ __launch_bounds__(256) void gemm_bf16(
    const u16* __restrict__ A, const u16* __restrict__ Bt, u16* __restrict__ C,
    float* __restrict__ Cf,
    int K, int lda, int ldb, int ldc, int nbn, const u16* __restrict__ lat) {
  __shared__ u16 As[128 * 64];
  __shared__ u16 Bs[128 * 64];
  int bm = blockIdx.x / nbn, bn = blockIdx.x % nbn;
  int m0 = bm * 128, n0 = bn * 128;
  int t = threadIdx.x;
  int lane = t & 63, wave = t >> 6;
  int wm = (wave >> 1) * 64, wn = (wave & 1) * 64;
  int lr = lane & 15, lg = lane >> 4;
  f32x4 acc[4][4] = {};
  for (int kt = 0; kt < K; kt += 64) {
    __syncthreads();
#pragma unroll
    for (int p = 0; p < 4; ++p) {
      int c = (p * 4 + wave) * 64 + lane;  // 0..1023 chunks of 16B
      int row = c >> 3, col = (c & 7) * 8;
      gld_lds16(A + (size_t)(m0 + row) * lda + kt + col, As + c * 8);
      gld_lds16(Bt + (size_t)(n0 + row) * ldb + kt + col, Bs + c * 8);
    }
    __syncthreads();
#pragma unroll
    for (int ks = 0; ks < 2; ++ks) {
      bf16x8 af[4], bj[4];
#pragma unroll
      for (int i = 0; i < 4; ++i)
        af[i] = *(const bf16x8*)(As + (wm + i * 16 + lr) * 64 + ks * 32 + lg * 8);
#pragma unroll
      for (int j = 0; j < 4; ++j)
        bj[j] = *(const bf16x8*)(Bs + (wn + j * 16 + lr) * 64 + ks * 32 + lg * 8);
#pragma unroll
      for (int i = 0; i < 4; ++i)
#pragma unroll
        for (int j = 0; j < 4; ++j)
          acc[i][j] = __builtin_amdgcn_mfma_f32_16x16x32_bf16(af[i], bj[j], acc[i][j], 0, 0, 0);
    }
  }
#pragma unroll
  for (int i = 0; i < 4; ++i)
#pragma unroll
    for (int j = 0; j < 4; ++j)
#pragma unroll
      for (int r = 0; r < 4; ++r) {
        int mm = m0 + wm + i * 16 + lg * 4 + r;
        int nn = n0 + wn + j * 16 + lr;
        float v = acc[i][j][r];
        if (lat) {
          int b = mm >> 11, s2 = mm & 2047;
          v += b2f(lat[(size_t)(b * 128 + (s2 & 127)) * 2048 + nn]);
        }
        if (Cf) Cf[(size_t)mm * ldc + nn] = v;
        else    C [(size_t)mm * ldc + nn] = f2b(v);
      }
}

// ---------- in-place RoPE, vectorized: 8 (lo,hi) pairs per thread ----------
__global__ __launch_bounds__(256) void rope_kernel(u16* __restrict__ proj, const float2* __restrict__ cs) {
  int u = blockIdx.x * 256 + threadIdx.x;   // 4096 rows * 160 octets = 655,360
  int row = u / 160;                        // b*2048 + s
  int slot = u - row * 160;                 // 0..159
  int h = slot >> 3;                        // head 0..19
  int i0 = (slot & 7) * 8;                  // 0,8,..,56
  int s = row & 2047;
  const float2* csrow = cs + (size_t)s * 64 + i0;
  u16* p = proj + (size_t)row * NPROJ + h * 128 + i0;
  uint4 lo4 = *(const uint4*)p;
  uint4 hi4 = *(const uint4*)(p + 64);
  u16* lo = (u16*)&lo4; u16* hi = (u16*)&hi4;
  u16 olo[8], ohi[8];
#pragma unroll
  for (int i = 0; i < 8; ++i) {
    float2 c = csrow[i];
    float a = b2f(lo[i]), b = b2f(hi[i]);
    olo[i] = f2b(a * c.x - b * c.y);
    ohi[i] = f2b(b * c.x + a * c.y);
  }
  *(uint4*)p        = *(uint4*)olo;
  *(uint4*)(p + 64) = *(uint4*)ohi;
}

// ---------- transpose V -> vt(b,kv,d,s) and kv_latent -> klt(b,l,s) ----------
__global__ __launch_bounds__(256) void transpose_v(const u16* __restrict__ proj,
                                                   u16* __restrict__ vt, u16* __restrict__ klt) {
  __shared__ u16 lds[64][80];
  int bid = blockIdx.x;
  int b = bid / 320, r = bid % 320;
  int ct = r / 32, st = r % 32;
  int c0 = ct < 8 ? 2560 + ct * 64 : 3200 + (ct - 8) * 64;
  int s0 = st * 64;
  int t = threadIdx.x;
  int srow = t >> 2, cg = (t & 3) * 16;
  const u16* p = proj + (size_t)(b * 2048 + s0 + srow) * NPROJ + c0 + cg;
  *(uint4*)&lds[srow][cg]     = *(const uint4*)p;
  *(uint4*)&lds[srow][cg + 8] = *(const uint4*)(p + 8);
  __syncthreads();
  int c = c0 + (t >> 2);
  int sg = (t & 3) * 16;
  u16 ov[16];
#pragma unroll
  for (int i = 0; i < 16; ++i) ov[i] = lds[sg + i][t >> 2];
  u16* dst;
  if (c < 3072) { int kv = (c - 2560) >> 7, d = (c - 2560) & 127;
                  dst = vt + ((size_t)(b * 4 + kv) * 128 + d) * 2048 + s0 + sg; }
  else          { int l = c - 3200;
                  dst = klt + (size_t)(b * 128 + l) * 2048 + s0 + sg; }
  *(uint4*)&dst[0] = *(uint4*)&ov[0];
  *(uint4*)&dst[8] = *(uint4*)&ov[8];
}

// ---------- flash attention (17 "heads": 16 GQA + 1 latent) ----------
// Single-wave blocks: max TLP for the latency-bound chain. K/V direct from L2.
// One wave = 16 q-rows; grid = 128 q-units x 34 (b,hh) groups, long work first.
__global__ __launch_bounds__(64, 4) void flash_attn(const u16* __restrict__ proj,
                                                    const u16* __restrict__ vt,
                                                    const u16* __restrict__ klt,
                                                    u16* __restrict__ acomb,
                                                    u16* __restrict__ latent) {
  __shared__ u16 Ps[16 * 72];     // wave-private P scratch [q][key], stride 72
  int bid = blockIdx.x;           // (127-qq)*34 + g
  int g = bid % 34;
  int qq = 127 - bid / 34;        // 16-row q-unit, descending work
  int hh = g % 17;
  int b  = g / 17;
  int lane = threadIdx.x;
  int lr = lane & 15, lg = lane >> 4;

  int qcol = hh < 16 ? hh * 128 : 3072;
  int kcol = hh < 16 ? 2048 + (hh >> 2) * 128 : 3200;
  const u16* vsrc = hh < 16 ? vt + (size_t)(b * 4 + (hh >> 2)) * 128 * 2048
                            : klt + (size_t)b * 128 * 2048;

  int qbase = qq * 16;
  const u16* qp = proj + (size_t)(b * 2048 + qbase) * NPROJ + qcol;
  bf16x8 aq[4];
#pragma unroll
  for (int ks = 0; ks < 4; ++ks)
    aq[ks] = *(const bf16x8*)(qp + (size_t)lr * NPROJ + ks * 32 + lg * 8);

  const u16* kbase = proj + (size_t)(b * 2048) * NPROJ + kcol;

  f32x4 o[8] = {};
  float m2[4]   = {-1e30f, -1e30f, -1e30f, -1e30f};
  float lsum[4] = {0.f, 0.f, 0.f, 0.f};
  const float scl = 0.08838834764831845f * 1.4426950408889634f;  // 128^-0.5 * log2e

  int nkt = qq >> 2;              // last key tile index
  for (int kt = 0; kt <= nkt; ++kt) {
    // scores: S = Q @ K^T  (16q x 64key), K fragments straight from L2
    const u16* kg = kbase + (size_t)(kt * 64) * NPROJ;
    f32x4 sv[4];
#pragma unroll
    for (int fr = 0; fr < 4; ++fr) {
      f32x4 a = {};
      const u16* krow = kg + (size_t)(fr * 16 + lr) * NPROJ + lg * 8;
#pragma unroll
      for (int ks = 0; ks < 4; ++ks) {
        bf16x8 bk = *(const bf16x8*)(krow + ks * 32);
        a = __builtin_amdgcn_mfma_f32_16x16x32_bf16(aq[ks], bk, a, 0, 0, 0);
      }
      sv[fr] = a;
    }
    // mask + scale (exp2 domain)
#pragma unroll
    for (int fr = 0; fr < 4; ++fr) {
      int key = kt * 64 + fr * 16 + lr;
#pragma unroll
      for (int r = 0; r < 4; ++r) {
        int q = qbase + lg * 4 + r;
        sv[fr][r] = (key <= q) ? sv[fr][r] * scl : -1e30f;
      }
    }
    // online softmax per row group
#pragma unroll
    for (int r = 0; r < 4; ++r) {
      float mx = fmaxf(fmaxf(sv[0][r], sv[1][r]), fmaxf(sv[2][r], sv[3][r]));
      mx = fmaxf(mx, __shfl_xor(mx, 1));
      mx = fmaxf(mx, __shfl_xor(mx, 2));
      mx = fmaxf(mx, __shfl_xor(mx, 4));
      mx = fmaxf(mx, __shfl_xor(mx, 8));
      float mn = fmaxf(m2[r], mx);
      float corr = exp2f(m2[r] - mn);
      m2[r] = mn;
      float rs = 0.f;
#pragma unroll
      for (int fr = 0; fr < 4; ++fr) {
        float pp = exp2f(sv[fr][r] - mn);
        sv[fr][r] = pp;
        rs += pp;
      }
      rs += __shfl_xor(rs, 1); rs += __shfl_xor(rs, 2);
      rs += __shfl_xor(rs, 4); rs += __shfl_xor(rs, 8);
      lsum[r] = lsum[r] * corr + rs;
#pragma unroll
      for (int cf = 0; cf < 8; ++cf) o[cf][r] *= corr;
    }
    // P -> wave-private LDS scratch (no barrier needed)
#pragma unroll
    for (int fr = 0; fr < 4; ++fr)
#pragma unroll
      for (int r = 0; r < 4; ++r) {
        int q = lg * 4 + r;
        int key = fr * 16 + lr;
        Ps[q * 72 + key] = f2b(sv[fr][r]);
      }
    // PV: O += P @ V   (A = P[16q x 64k], B = V^T[d][k] straight from L2)
    const u16* vg = vsrc + kt * 64 + lg * 8;
#pragma unroll
    for (int ks = 0; ks < 2; ++ks) {
      bf16x8 ap = *(const bf16x8*)(Ps + lr * 72 + ks * 32 + lg * 8);
#pragma unroll
      for (int cf = 0; cf < 8; ++cf) {
        bf16x8 bv = *(const bf16x8*)(vg + (size_t)(cf * 16 + lr) * 2048 + ks * 32);
        o[cf] = __builtin_amdgcn_mfma_f32_16x16x32_bf16(ap, bv, o[cf], 0, 0, 0);
      }
    }
  }
  // epilogue
  u16* obase; size_t ostride;
  if (hh < 16) { obase = acomb + hh * 128; ostride = 2048; }
  else         { obase = latent;           ostride = 128; }
#pragma unroll
  for (int r = 0; r < 4; ++r) {
    float inv = 1.0f / lsum[r];
    int q = qbase + lg * 4 + r;
    u16* orow = obase + (size_t)(b * 2048 + q) * ostride;
#pragma unroll
    for (int cf = 0; cf < 8; ++cf)
      orow[cf * 16 + lr] = f2b(o[cf][r] * inv);
  }
}

// ---------- launch ----------
extern "C" void kernel_launch(void* const* d_in, const int* in_sizes, int n_in,
                              void* d_out, int out_size, void* d_ws, size_t ws_size,
                              hipStream_t stream) {
  const float* x   = (const float*)d_in[0];
  // d_in[1] mask (tril int32, start_pos=0) — causality hardcoded
  const float* wq  = (const float*)d_in[2];
  const float* wk  = (const float*)d_in[3];
  const float* wv  = (const float*)d_in[4];
  const float* wql = (const float*)d_in[5];
  const float* wkl = (const float*)d_in[6];
  const float* wo  = (const float*)d_in[7];
  // d_in[8] start_pos == 0

  // Workspace layout (55 MiB peak), lifetimes carefully aliased:
  //   proj   @        0 : 27,262,976  (GEMM1 -> flash);  wt2 (8.4MB) aliases @0 after flash
  //   wt1    @ 27262976 : 13,631,488  (GEMM1 only); afterwards this region holds:
  //       cs     @ 27262976 : 1,048,576
  //       vt     @ 28311552 : 4,194,304
  //       klt    @ 32505856 : 1,048,576
  //       latent @ 33554432 : 1,048,576
  //       lout   @ 34603008 : 1,048,576   (ends 35,651,584 < 40,894,464)
  //   xb     @ 40894464 : 16,777,216  (cvt_x -> GEMM1); acomb aliases after GEMM1
  //   total 57,671,680 bytes
  char* ws = (char*)d_ws;
  u16*    proj  = (u16*)(ws + 0);
  u16*    wt2   = (u16*)(ws + 0);
  u16*    wt1   = (u16*)(ws + 27262976);
  float2* cs    = (float2*)(ws + 27262976);
  u16*    vt    = (u16*)(ws + 28311552);
  u16*    klt   = (u16*)(ws + 32505856);
  u16*    latent= (u16*)(ws + 33554432);
  u16*    lout  = (u16*)(ws + 34603008);
  u16*    xb    = (u16*)(ws + 40894464);
  u16*    acomb = (u16*)(ws + 40894464);
  float*  out   = (float*)d_out;

  prep_wt1<<<52 * 32, 256, 0, stream>>>(wq, wk, wv, wql, wkl, wt1);
  cvt_x<<<8192, 256, 0, stream>>>(x, xb);
  // proj = x @ [wq|wk|wv|wql|wkl]
  gemm_bf16<<<32 * 26, 256, 0, stream>>>(xb, wt1, proj, nullptr, 2048, 2048, 2048, NPROJ, 26, nullptr);
  rope_table<<<512, 256, 0, stream>>>(cs);          // wt1 dead from here
  rope_kernel<<<2560, 256, 0, stream>>>(proj, cs);
  transpose_v<<<640, 256, 0, stream>>>(proj, vt, klt);
  flash_attn<<<128 * 34, 64, 0, stream>>>(proj, vt, klt, acomb, latent);  // xb dead
  // wt2 = wo^T (into dead proj space)
  prep_wt2<<<32 * 32, 256, 0, stream>>>(wo, wt2);
  // lout = view(latent,(2x128,2048)) @ wo   (bf16 out)
  gemm_bf16<<<2 * 16, 256, 0, stream>>>(latent, wt2, lout, nullptr, 2048, 2048, 2048, 2048, 16, nullptr);
  // out(f32) = acomb @ wo + lout[b, s&127]  (latent reshape-scramble fused)
  gemm_bf16<<<32 * 16, 256, 0, stream>>>(acomb, wt2, nullptr, out, 2048, 2048, 2048, 2048, 16, lout);
}